// Round 19
// baseline (316.351 us; speedup 1.0000x reference)
//
#include <hip/hip_runtime.h>

// ScaledDotProductAttention: B=4 H=12 S=2048 DK=64, fp32 in/out.
// d_out = context [B,H,S,DK] then attn [B,H,S,S], concatenated.
//
// R18 = R17 (best: 260.7us) with the attn flush LDS round-trip removed:
// P values are stored to global DIRECTLY from the f32 registers where they
// are computed (float4 per lane-group piece, 64B contiguous per row), and
// pbw is only used for PV staging. Removes ~2MB/block LDS reads + unpack.

#define S_LEN 2048
#define D_K   64
#define NBH   48
#define VT_STRIDE 2080
#define CH    128          // keys per staged chunk (sweep 2)
#define NCHUNK (S_LEN / CH)
#define CH1   256          // keys per staged chunk (sweep 1)
#define NCH1  (S_LEN / CH1)

typedef __attribute__((ext_vector_type(8))) short short8v;   // 8 x bf16
typedef __attribute__((ext_vector_type(4))) short short4v;   // 4 x bf16
typedef __attribute__((ext_vector_type(4))) float float4v;

__device__ inline unsigned short f2bf(float f) {
    union { float f; unsigned u; } c; c.f = f;
    unsigned u = c.u;
    return (unsigned short)((u + 0x7FFFu + ((u >> 16) & 1u)) >> 16);  // RNE
}

// LDS-visibility barrier WITHOUT vmcnt drain: global stores stay in flight.
__device__ inline void wg_sync_lds() {
    asm volatile("s_waitcnt lgkmcnt(0)" ::: "memory");
    __builtin_amdgcn_s_barrier();
    __builtin_amdgcn_sched_barrier(0);
}

#define CEXP 0.18033688011112042f   // (1/sqrt(64)) * log2(e)

// ---------------- prepass: K f32 -> bf16 ----------------
__global__ __launch_bounds__(256)
void conv_k_kernel(const float* __restrict__ K, unsigned short* __restrict__ Kbf) {
    const size_t N = (size_t)NBH * S_LEN * D_K;
    for (size_t i = ((size_t)blockIdx.x * 256 + threadIdx.x) * 4; i < N;
         i += (size_t)gridDim.x * 256 * 4) {
        float4v v = *reinterpret_cast<const float4v*>(K + i);
        unsigned p0 = (unsigned)f2bf(v[0]) | ((unsigned)f2bf(v[1]) << 16);
        unsigned p1 = (unsigned)f2bf(v[2]) | ((unsigned)f2bf(v[3]) << 16);
        uint2 pk; pk.x = p0; pk.y = p1;
        *reinterpret_cast<uint2*>(Kbf + i) = pk;
    }
}

// ---------------- prepass: V [bh][k][d] f32 -> VT [bh][d][k_pad] bf16 ----------------
__global__ __launch_bounds__(256)
void trans_v_kernel(const float* __restrict__ V, unsigned short* __restrict__ VT) {
    const int bh = blockIdx.y;
    const int k0 = blockIdx.x * 64;
    __shared__ unsigned short tile[64][66];
    const int t = threadIdx.x;
    {
        const int kr = t >> 2, dq = t & 3;
        const float* src = V + (size_t)bh * S_LEN * D_K + (size_t)(k0 + kr) * D_K + dq * 16;
        #pragma unroll
        for (int i = 0; i < 4; ++i) {
            float4v v = *reinterpret_cast<const float4v*>(src + i * 4);
            #pragma unroll
            for (int j = 0; j < 4; ++j) tile[kr][dq * 16 + i * 4 + j] = f2bf(v[j]);
        }
    }
    __syncthreads();
    {
        const int d = t >> 2, kq = t & 3;
        unsigned pk[8];
        #pragma unroll
        for (int i = 0; i < 8; ++i) {
            unsigned lo = tile[kq * 16 + 2 * i][d];
            unsigned hi = tile[kq * 16 + 2 * i + 1][d];
            pk[i] = lo | (hi << 16);
        }
        unsigned* dst = reinterpret_cast<unsigned*>(
            VT + (size_t)bh * D_K * VT_STRIDE + (size_t)d * VT_STRIDE + k0 + kq * 16);
        uint4 a; a.x = pk[0]; a.y = pk[1]; a.z = pk[2]; a.w = pk[3];
        uint4 b; b.x = pk[4]; b.y = pk[5]; b.z = pk[6]; b.w = pk[7];
        reinterpret_cast<uint4*>(dst)[0] = a;
        reinterpret_cast<uint4*>(dst)[1] = b;
    }
}

// ---------------- fused kernel ----------------
// Grid (16, 48), 256 thr (4 waves). Wave w owns q-rows [qt*128 + w*32, +32)
// as two groups A/B of 16; all 2048 keys. Swapped QK^T per group:
// lane holds P[q=lq][k = kt*16 + lg*4 + r].
__global__ __launch_bounds__(256, 3)
void sdpa_fused_kernel(const float* __restrict__ Qp,
                       const unsigned short* __restrict__ Kbf,
                       const unsigned short* __restrict__ VT,
                       float* __restrict__ ctx, float* __restrict__ attn) {
    const int qt   = blockIdx.x;   // 0..15
    const int bh   = blockIdx.y;   // 0..47
    const int tid  = threadIdx.x;
    const int w    = tid >> 6;     // 0..3
    const int lane = tid & 63;
    const int lq   = lane & 15;
    const int lg   = lane >> 4;
    const int qg0  = qt * 128 + w * 32;   // group A rows; group B = +16
    const size_t base = (size_t)bh * S_LEN * D_K;

    // sbuf: 32KB. Sweep1: [256 keys][64 d]. Sweep2: kbuf=sbuf ([128k][64d],16KB),
    // vbuf=sbuf+8192 ([64 d][128 k] rows 256B, 16KB).
    // Row swizzles: K rows byte^=((row&7)<<4); V rows byte^=((row&15)<<4).
    __shared__ __align__(16) unsigned short sbuf[256 * 64];
    __shared__ __align__(16) unsigned short pbw[4][32][40];
    unsigned short* kbuf = sbuf;
    unsigned short* vbuf = sbuf + 128 * 64;

    // ---- Q fragments for both groups (row qg0+lq and qg0+16+lq)
    short8v qa0, qa1, qb0, qb1;
    {
        const float* qrA = Qp + base + (size_t)(qg0 + lq) * D_K + lg * 8;
        const float* qrB = qrA + (size_t)16 * D_K;
        float4v a0 = *reinterpret_cast<const float4v*>(qrA);
        float4v a1 = *reinterpret_cast<const float4v*>(qrA + 4);
        float4v a2 = *reinterpret_cast<const float4v*>(qrA + 32);
        float4v a3 = *reinterpret_cast<const float4v*>(qrA + 36);
        float4v b0 = *reinterpret_cast<const float4v*>(qrB);
        float4v b1 = *reinterpret_cast<const float4v*>(qrB + 4);
        float4v b2 = *reinterpret_cast<const float4v*>(qrB + 32);
        float4v b3 = *reinterpret_cast<const float4v*>(qrB + 36);
        #pragma unroll
        for (int j = 0; j < 4; ++j) {
            qa0[j]     = (short)f2bf(a0[j]);
            qa0[4 + j] = (short)f2bf(a1[j]);
            qa1[j]     = (short)f2bf(a2[j]);
            qa1[4 + j] = (short)f2bf(a3[j]);
            qb0[j]     = (short)f2bf(b0[j]);
            qb0[4 + j] = (short)f2bf(b1[j]);
            qb1[j]     = (short)f2bf(b2[j]);
            qb1[4 + j] = (short)f2bf(b3[j]);
        }
    }

    // K staging (sweep 2): 256 thr, 4 pieces (rows tid>>2 and +64, bytes (tid&3)*16, +64)
    const int krow  = tid >> 2;             // 0..63
    const int kby0  = (tid & 3) * 16;
    const int ksw   = (krow & 7) << 4;      // same for krow and krow+64
    const int kbiA0 = krow * 64 + (((kby0)      ^ ksw) >> 1);
    const int kbiA1 = krow * 64 + (((kby0 + 64) ^ ksw) >> 1);
    const int kbiB0 = (krow + 64) * 64 + (((kby0)      ^ ksw) >> 1);
    const int kbiB1 = (krow + 64) * 64 + (((kby0 + 64) ^ ksw) >> 1);
    const unsigned short* ksrcb = Kbf + base + (size_t)krow * D_K + (kby0 >> 1);

    // V staging: 4 pieces (row tid>>2, bytes (tid&3)*16 + j*64)
    const int vrow  = tid >> 2;             // 0..63
    const int vsw   = (vrow & 15) << 4;
    const int vby0  = (tid & 3) * 16;
    int vbi[4];
    #pragma unroll
    for (int j = 0; j < 4; ++j)
        vbi[j] = vrow * 128 + (((vby0 + j * 64) ^ vsw) >> 1);
    const unsigned short* vsrcb = VT + (size_t)bh * D_K * VT_STRIDE
                                     + (size_t)vrow * VT_STRIDE + (vby0 >> 1);

    // read-side swizzle constants
    const int kswz = (lq & 7) << 4;
    const int koff0 = ((lg * 16)      ^ kswz) >> 1;
    const int koff1 = ((64 + lg * 16) ^ kswz) >> 1;
    const int vswz = lq << 4;

    // ================= sweep 1: row sums (CH1=256, 8 chunks, both groups share K reads)
    float sA0 = 0.f, sA1 = 0.f, sB0 = 0.f, sB1 = 0.f;
    for (int c = 0; c < NCH1; ++c) {
        const unsigned short* kc = ksrcb + (size_t)c * CH1 * D_K;
        short8v r0 = *reinterpret_cast<const short8v*>(kc);
        short8v r1 = *reinterpret_cast<const short8v*>(kc + 32);
        short8v r2 = *reinterpret_cast<const short8v*>(kc + (size_t)64 * D_K);
        short8v r3 = *reinterpret_cast<const short8v*>(kc + (size_t)64 * D_K + 32);
        short8v r4 = *reinterpret_cast<const short8v*>(kc + (size_t)128 * D_K);
        short8v r5 = *reinterpret_cast<const short8v*>(kc + (size_t)128 * D_K + 32);
        short8v r6 = *reinterpret_cast<const short8v*>(kc + (size_t)192 * D_K);
        short8v r7 = *reinterpret_cast<const short8v*>(kc + (size_t)192 * D_K + 32);
        wg_sync_lds();
        *reinterpret_cast<short8v*>(&sbuf[kbiA0]) = r0;
        *reinterpret_cast<short8v*>(&sbuf[kbiA1]) = r1;
        *reinterpret_cast<short8v*>(&sbuf[kbiB0]) = r2;
        *reinterpret_cast<short8v*>(&sbuf[kbiB1]) = r3;
        *reinterpret_cast<short8v*>(&sbuf[8192 + kbiA0]) = r4;
        *reinterpret_cast<short8v*>(&sbuf[8192 + kbiA1]) = r5;
        *reinterpret_cast<short8v*>(&sbuf[8192 + kbiB0]) = r6;
        *reinterpret_cast<short8v*>(&sbuf[8192 + kbiB1]) = r7;
        wg_sync_lds();
        #pragma unroll
        for (int kt = 0; kt < 16; ++kt) {
            const int kl = kt * 16 + lq;
            short8v k0 = *reinterpret_cast<const short8v*>(&sbuf[kl * 64 + koff0]);
            short8v k1 = *reinterpret_cast<const short8v*>(&sbuf[kl * 64 + koff1]);
            float4v aA = (float4v)0.0f, aB = (float4v)0.0f;
            aA = __builtin_amdgcn_mfma_f32_16x16x32_bf16(k0, qa0, aA, 0, 0, 0);
            aA = __builtin_amdgcn_mfma_f32_16x16x32_bf16(k1, qa1, aA, 0, 0, 0);
            aB = __builtin_amdgcn_mfma_f32_16x16x32_bf16(k0, qb0, aB, 0, 0, 0);
            aB = __builtin_amdgcn_mfma_f32_16x16x32_bf16(k1, qb1, aB, 0, 0, 0);
            sA0 += exp2f(aA[0] * CEXP) + exp2f(aA[1] * CEXP);
            sA1 += exp2f(aA[2] * CEXP) + exp2f(aA[3] * CEXP);
            sB0 += exp2f(aB[0] * CEXP) + exp2f(aB[1] * CEXP);
            sB1 += exp2f(aB[2] * CEXP) + exp2f(aB[3] * CEXP);
        }
    }
    float sA = sA0 + sA1, sB = sB0 + sB1;
    sA += __shfl_xor(sA, 16, 64);
    sA += __shfl_xor(sA, 32, 64);
    sB += __shfl_xor(sB, 16, 64);
    sB += __shfl_xor(sB, 32, 64);
    const float rsA = 1.0f / sA;
    const float rsB = 1.0f / sB;

    // ================= sweep 2: attn + PV + ctx =================
    float4v caccA[4], caccB[4];
    #pragma unroll
    for (int dt = 0; dt < 4; ++dt) { caccA[dt] = (float4v)0.0f; caccB[dt] = (float4v)0.0f; }

    // per-lane attn row bases (loop-invariant)
    float* attnbA = attn + (size_t)bh * S_LEN * S_LEN + (size_t)(qg0 + lq) * S_LEN + lg * 4;
    float* attnbB = attnbA + (size_t)16 * S_LEN;

    for (int c = 0; c < NCHUNK; ++c) {
        const unsigned short* kc = ksrcb + (size_t)c * CH * D_K;
        short8v r0 = *reinterpret_cast<const short8v*>(kc);
        short8v r1 = *reinterpret_cast<const short8v*>(kc + 32);
        short8v r2 = *reinterpret_cast<const short8v*>(kc + (size_t)64 * D_K);
        short8v r3 = *reinterpret_cast<const short8v*>(kc + (size_t)64 * D_K + 32);
        short8v v0 = *reinterpret_cast<const short8v*>(vsrcb + c * CH);
        short8v v1 = *reinterpret_cast<const short8v*>(vsrcb + c * CH + 32);
        short8v v2 = *reinterpret_cast<const short8v*>(vsrcb + c * CH + 64);
        short8v v3 = *reinterpret_cast<const short8v*>(vsrcb + c * CH + 96);
        wg_sync_lds();
        *reinterpret_cast<short8v*>(&kbuf[kbiA0]) = r0;
        *reinterpret_cast<short8v*>(&kbuf[kbiA1]) = r1;
        *reinterpret_cast<short8v*>(&kbuf[kbiB0]) = r2;
        *reinterpret_cast<short8v*>(&kbuf[kbiB1]) = r3;
        *reinterpret_cast<short8v*>(&vbuf[vbi[0]]) = v0;
        *reinterpret_cast<short8v*>(&vbuf[vbi[1]]) = v1;
        *reinterpret_cast<short8v*>(&vbuf[vbi[2]]) = v2;
        *reinterpret_cast<short8v*>(&vbuf[vbi[3]]) = v3;
        wg_sync_lds();

        #pragma unroll
        for (int s2 = 0; s2 < 4; ++s2) {
            // 2 score tiles -> attn f32 stores DIRECT from regs + bf16 P into pbw
            #pragma unroll
            for (int t = 0; t < 2; ++t) {
                const int kt = s2 * 2 + t;
                const int kl = kt * 16 + lq;
                short8v k0 = *reinterpret_cast<const short8v*>(&kbuf[kl * 64 + koff0]);
                short8v k1 = *reinterpret_cast<const short8v*>(&kbuf[kl * 64 + koff1]);
                float4v aA = (float4v)0.0f, aB = (float4v)0.0f;
                aA = __builtin_amdgcn_mfma_f32_16x16x32_bf16(k0, qa0, aA, 0, 0, 0);
                aA = __builtin_amdgcn_mfma_f32_16x16x32_bf16(k1, qa1, aA, 0, 0, 0);
                aB = __builtin_amdgcn_mfma_f32_16x16x32_bf16(k0, qb0, aB, 0, 0, 0);
                aB = __builtin_amdgcn_mfma_f32_16x16x32_bf16(k1, qb1, aB, 0, 0, 0);
                float4v pA, pB;
                #pragma unroll
                for (int r = 0; r < 4; ++r) {
                    pA[r] = exp2f(aA[r] * CEXP) * rsA;
                    pB[r] = exp2f(aB[r] * CEXP) * rsB;
                }
                const int koffg = c * CH + kt * 16;
                *reinterpret_cast<float4v*>(attnbA + koffg) = pA;
                *reinterpret_cast<float4v*>(attnbB + koffg) = pB;
                uint2 hA, hB;
                hA.x = (unsigned)f2bf(pA[0]) | ((unsigned)f2bf(pA[1]) << 16);
                hA.y = (unsigned)f2bf(pA[2]) | ((unsigned)f2bf(pA[3]) << 16);
                hB.x = (unsigned)f2bf(pB[0]) | ((unsigned)f2bf(pB[1]) << 16);
                hB.y = (unsigned)f2bf(pB[2]) | ((unsigned)f2bf(pB[3]) << 16);
                *reinterpret_cast<uint2*>(&pbw[w][lq][t * 16 + lg * 4]) = hA;
                *reinterpret_cast<uint2*>(&pbw[w][16 + lq][t * 16 + lg * 4]) = hB;
            }
            // PV: bv read ONCE, used by both groups
            short8v paA = *reinterpret_cast<const short8v*>(&pbw[w][lq][lg * 8]);
            short8v paB = *reinterpret_cast<const short8v*>(&pbw[w][16 + lq][lg * 8]);
            #pragma unroll
            for (int dt = 0; dt < 4; ++dt) {
                const int d = dt * 16 + lq;
                short8v bv = *reinterpret_cast<const short8v*>(
                    &vbuf[d * 128 + (((s2 * 64 + lg * 16) ^ vswz) >> 1)]);
                caccA[dt] = __builtin_amdgcn_mfma_f32_16x16x32_bf16(paA, bv, caccA[dt], 0, 0, 0);
                caccB[dt] = __builtin_amdgcn_mfma_f32_16x16x32_bf16(paB, bv, caccB[dt], 0, 0, 0);
            }
        }
    }

    // ---- ctx: wave-owned rows, direct stores
    float* ctxb = ctx + base;
    #pragma unroll
    for (int dt = 0; dt < 4; ++dt)
        #pragma unroll
        for (int r = 0; r < 4; ++r) {
            ctxb[(size_t)(qg0 + lg * 4 + r) * D_K + dt * 16 + lq] = caccA[dt][r];
            ctxb[(size_t)(qg0 + 16 + lg * 4 + r) * D_K + dt * 16 + lq] = caccB[dt][r];
        }
}

// ---------------- fallback (no workspace): self-contained ----------------
__global__ __launch_bounds__(512)
void sdpa_fallback_kernel(const float* __restrict__ Qp, const float* __restrict__ Kp,
                          const float* __restrict__ Vp,
                          float* __restrict__ ctx, float* __restrict__ attn) {
    const int qt = blockIdx.x, bh = blockIdx.y, tid = threadIdx.x;
    const int w = tid >> 6, lane = tid & 63, lq = lane & 15, lg = lane >> 4;
    const int qg = qt * 16, kw = w * 256;
    const size_t base = (size_t)bh * S_LEN * D_K;
    __shared__ __align__(16) char smem_raw[8 * 16 * 136 * 2];
    __shared__ float red_s[16][8];
    auto pbuf = reinterpret_cast<unsigned short(*)[16][136]>(smem_raw);
    auto ctxp = reinterpret_cast<float(*)[16][64]>(smem_raw);

    short8v q0, q1;
    {
        const float* qr = Qp + base + (size_t)(qg + lq) * D_K + lg * 8;
        #pragma unroll
        for (int j = 0; j < 8; ++j) { q0[j] = (short)f2bf(qr[j]); q1[j] = (short)f2bf(qr[32 + j]); }
    }
    float4v acc[16];
    #pragma unroll
    for (int kt = 0; kt < 16; ++kt) acc[kt] = (float4v)0.0f;
    #pragma unroll
    for (int kt = 0; kt < 16; ++kt) {
        const float* kr = Kp + base + (size_t)(kw + kt * 16 + lq) * D_K + lg * 8;
        short8v k0, k1;
        #pragma unroll
        for (int j = 0; j < 8; ++j) { k0[j] = (short)f2bf(kr[j]); k1[j] = (short)f2bf(kr[32 + j]); }
        acc[kt] = __builtin_amdgcn_mfma_f32_16x16x32_bf16(k0, q0, acc[kt], 0, 0, 0);
        acc[kt] = __builtin_amdgcn_mfma_f32_16x16x32_bf16(k1, q1, acc[kt], 0, 0, 0);
    }
    float s = 0.f;
    #pragma unroll
    for (int kt = 0; kt < 16; ++kt)
        #pragma unroll
        for (int r = 0; r < 4; ++r) {
            float p = exp2f(acc[kt][r] * CEXP);
            acc[kt][r] = p; s += p;
        }
    s += __shfl_xor(s, 16, 64);
    s += __shfl_xor(s, 32, 64);
    if (lane < 16) red_s[lane][w] = s;
    __syncthreads();
    float gs = red_s[lq][0];
    #pragma unroll
    for (int ww = 1; ww < 8; ++ww) gs += red_s[lq][ww];
    const float rsv = 1.0f / gs;
    #pragma unroll
    for (int kt = 0; kt < 16; ++kt) acc[kt] = acc[kt] * rsv;

    float4v cacc[4];
    #pragma unroll
    for (int dt = 0; dt < 4; ++dt) cacc[dt] = (float4v)0.0f;
    #pragma unroll
    for (int half = 0; half < 2; ++half) {
        #pragma unroll
        for (int kth = 0; kth < 8; ++kth) {
            const int kt = half * 8 + kth;
            unsigned p01 = (unsigned)f2bf(acc[kt][0]) | ((unsigned)f2bf(acc[kt][1]) << 16);
            unsigned p23 = (unsigned)f2bf(acc[kt][2]) | ((unsigned)f2bf(acc[kt][3]) << 16);
            unsigned* dst = reinterpret_cast<unsigned*>(&pbuf[w][lq][kth * 16 + lg * 4]);
            dst[0] = p01; dst[1] = p23;
        }
        #pragma unroll
        for (int s2 = 0; s2 < 4; ++s2) {
            short8v pa = *reinterpret_cast<const short8v*>(&pbuf[w][lq][s2 * 32 + lg * 8]);
            const int kk = kw + half * 128 + s2 * 32 + lg * 8;
            #pragma unroll
            for (int dt = 0; dt < 4; ++dt) {
                short8v bv;
                #pragma unroll
                for (int j = 0; j < 8; ++j)
                    bv[j] = (short)f2bf(Vp[base + (size_t)(kk + j) * D_K + dt * 16 + lq]);
                cacc[dt] = __builtin_amdgcn_mfma_f32_16x16x32_bf16(pa, bv, cacc[dt], 0, 0, 0);
            }
        }
    }
    __syncthreads();
    #pragma unroll
    for (int dt = 0; dt < 4; ++dt)
        #pragma unroll
        for (int r = 0; r < 4; ++r)
            ctxp[w][lg * 4 + r][dt * 16 + lq] = cacc[dt][r];
    __syncthreads();
    float* ctxb = ctx + base;
    for (int idx = tid; idx < 16 * 64; idx += 512) {
        const int q = idx >> 6, d = idx & 63;
        float sum = 0.f;
        #pragma unroll
        for (int ww = 0; ww < 8; ++ww) sum += ctxp[ww][q][d];
        ctxb[(size_t)(qg + q) * D_K + d] = sum;
    }
    float* attnb = attn + (size_t)bh * S_LEN * S_LEN + (size_t)(qg + lq) * S_LEN + kw + lg * 4;
    #pragma unroll
    for (int kt = 0; kt < 16; ++kt)
        *reinterpret_cast<float4v*>(attnb + kt * 16) = acc[kt];
}

extern "C" void kernel_launch(void* const* d_in, const int* in_sizes, int n_in,
                              void* d_out, int out_size, void* d_ws, size_t ws_size,
                              hipStream_t stream) {
    const float* Q = (const float*)d_in[0];
    const float* K = (const float*)d_in[1];
    const float* V = (const float*)d_in[2];
    float* ctx  = (float*)d_out;
    float* attn = ctx + (size_t)NBH * S_LEN * D_K;

    const size_t nel  = (size_t)NBH * S_LEN * D_K;       // 6,291,456
    const size_t nvt  = (size_t)NBH * D_K * VT_STRIDE;
    const size_t need = (nel + nvt) * 2;

    if (ws_size >= need) {
        unsigned short* Kbf = (unsigned short*)d_ws;
        unsigned short* VT  = Kbf + nel;
        conv_k_kernel<<<2048, 256, 0, stream>>>(K, Kbf);
        trans_v_kernel<<<dim3(32, 48), 256, 0, stream>>>(V, VT);
        sdpa_fused_kernel<<<dim3(16, 48), 256, 0, stream>>>(Q, Kbf, VT, ctx, attn);
    } else {
        sdpa_fallback_kernel<<<dim3(128, 48), 512, 0, stream>>>(Q, K, V, ctx, attn);
    }
}

// Round 20
// 260.054 us; speedup vs baseline: 1.2165x; 1.2165x over previous
//
#include <hip/hip_runtime.h>

// ScaledDotProductAttention: B=4 H=12 S=2048 DK=64, fp32 in/out.
// d_out = context [B,H,S,DK] then attn [B,H,S,S], concatenated.
//
// FINAL (R19) = exact R17, the best measured configuration (260.7us):
//  - prepasses: K->bf16, V->V^T bf16 (padded rows, breaks channel camping)
//  - fused kernel: grid (16,48), 4 waves x 2 q-groups of 16 rows (K/V LDS
//    fragment reads shared by 2 MFMAs), swizzled dense LDS staging,
//    no-max softmax (2-pass row sums), lgkm-only barriers (stores never
//    drained), LDS-transposed 128B-contiguous attn flush, direct ctx stores.
// R18's direct-from-register attn stores regressed (64B strided pieces);
// the LDS-transposed flush is the better store path.

#define S_LEN 2048
#define D_K   64
#define NBH   48
#define VT_STRIDE 2080
#define CH    128          // keys per staged chunk (sweep 2)
#define NCHUNK (S_LEN / CH)
#define CH1   256          // keys per staged chunk (sweep 1)
#define NCH1  (S_LEN / CH1)

typedef __attribute__((ext_vector_type(8))) short short8v;   // 8 x bf16
typedef __attribute__((ext_vector_type(4))) short short4v;   // 4 x bf16
typedef __attribute__((ext_vector_type(4))) float float4v;

__device__ inline unsigned short f2bf(float f) {
    union { float f; unsigned u; } c; c.f = f;
    unsigned u = c.u;
    return (unsigned short)((u + 0x7FFFu + ((u >> 16) & 1u)) >> 16);  // RNE
}
__device__ inline float bf2f(unsigned short h) {
    union { unsigned u; float f; } c; c.u = ((unsigned)h) << 16; return c.f;
}

// LDS-visibility barrier WITHOUT vmcnt drain: global stores stay in flight.
__device__ inline void wg_sync_lds() {
    asm volatile("s_waitcnt lgkmcnt(0)" ::: "memory");
    __builtin_amdgcn_s_barrier();
    __builtin_amdgcn_sched_barrier(0);
}

#define CEXP 0.18033688011112042f   // (1/sqrt(64)) * log2(e)

// ---------------- prepass: K f32 -> bf16 ----------------
__global__ __launch_bounds__(256)
void conv_k_kernel(const float* __restrict__ K, unsigned short* __restrict__ Kbf) {
    const size_t N = (size_t)NBH * S_LEN * D_K;
    for (size_t i = ((size_t)blockIdx.x * 256 + threadIdx.x) * 4; i < N;
         i += (size_t)gridDim.x * 256 * 4) {
        float4v v = *reinterpret_cast<const float4v*>(K + i);
        unsigned p0 = (unsigned)f2bf(v[0]) | ((unsigned)f2bf(v[1]) << 16);
        unsigned p1 = (unsigned)f2bf(v[2]) | ((unsigned)f2bf(v[3]) << 16);
        uint2 pk; pk.x = p0; pk.y = p1;
        *reinterpret_cast<uint2*>(Kbf + i) = pk;
    }
}

// ---------------- prepass: V [bh][k][d] f32 -> VT [bh][d][k_pad] bf16 ----------------
__global__ __launch_bounds__(256)
void trans_v_kernel(const float* __restrict__ V, unsigned short* __restrict__ VT) {
    const int bh = blockIdx.y;
    const int k0 = blockIdx.x * 64;
    __shared__ unsigned short tile[64][66];
    const int t = threadIdx.x;
    {
        const int kr = t >> 2, dq = t & 3;
        const float* src = V + (size_t)bh * S_LEN * D_K + (size_t)(k0 + kr) * D_K + dq * 16;
        #pragma unroll
        for (int i = 0; i < 4; ++i) {
            float4v v = *reinterpret_cast<const float4v*>(src + i * 4);
            #pragma unroll
            for (int j = 0; j < 4; ++j) tile[kr][dq * 16 + i * 4 + j] = f2bf(v[j]);
        }
    }
    __syncthreads();
    {
        const int d = t >> 2, kq = t & 3;
        unsigned pk[8];
        #pragma unroll
        for (int i = 0; i < 8; ++i) {
            unsigned lo = tile[kq * 16 + 2 * i][d];
            unsigned hi = tile[kq * 16 + 2 * i + 1][d];
            pk[i] = lo | (hi << 16);
        }
        unsigned* dst = reinterpret_cast<unsigned*>(
            VT + (size_t)bh * D_K * VT_STRIDE + (size_t)d * VT_STRIDE + k0 + kq * 16);
        uint4 a; a.x = pk[0]; a.y = pk[1]; a.z = pk[2]; a.w = pk[3];
        uint4 b; b.x = pk[4]; b.y = pk[5]; b.z = pk[6]; b.w = pk[7];
        reinterpret_cast<uint4*>(dst)[0] = a;
        reinterpret_cast<uint4*>(dst)[1] = b;
    }
}

// ---------------- fused kernel ----------------
// Grid (16, 48), 256 thr (4 waves). Wave w owns q-rows [qt*128 + w*32, +32)
// as two groups A/B of 16; all 2048 keys. Swapped QK^T per group:
// lane holds P[q=lq][k = kt*16 + lg*4 + r].
__global__ __launch_bounds__(256, 3)
void sdpa_fused_kernel(const float* __restrict__ Qp,
                       const unsigned short* __restrict__ Kbf,
                       const unsigned short* __restrict__ VT,
                       float* __restrict__ ctx, float* __restrict__ attn) {
    const int qt   = blockIdx.x;   // 0..15
    const int bh   = blockIdx.y;   // 0..47
    const int tid  = threadIdx.x;
    const int w    = tid >> 6;     // 0..3
    const int lane = tid & 63;
    const int lq   = lane & 15;
    const int lg   = lane >> 4;
    const int qg0  = qt * 128 + w * 32;   // group A rows; group B = +16
    const size_t base = (size_t)bh * S_LEN * D_K;

    // sbuf: 32KB. Sweep1: [256 keys][64 d]. Sweep2: kbuf=sbuf ([128k][64d],16KB),
    // vbuf=sbuf+8192 ([64 d][128 k] rows 256B, 16KB).
    // Row swizzles: K rows byte^=((row&7)<<4); V rows byte^=((row&15)<<4).
    __shared__ __align__(16) unsigned short sbuf[256 * 64];
    __shared__ __align__(16) unsigned short pbw[4][32][40];
    unsigned short* kbuf = sbuf;
    unsigned short* vbuf = sbuf + 128 * 64;

    // ---- Q fragments for both groups (row qg0+lq and qg0+16+lq)
    short8v qa0, qa1, qb0, qb1;
    {
        const float* qrA = Qp + base + (size_t)(qg0 + lq) * D_K + lg * 8;
        const float* qrB = qrA + (size_t)16 * D_K;
        float4v a0 = *reinterpret_cast<const float4v*>(qrA);
        float4v a1 = *reinterpret_cast<const float4v*>(qrA + 4);
        float4v a2 = *reinterpret_cast<const float4v*>(qrA + 32);
        float4v a3 = *reinterpret_cast<const float4v*>(qrA + 36);
        float4v b0 = *reinterpret_cast<const float4v*>(qrB);
        float4v b1 = *reinterpret_cast<const float4v*>(qrB + 4);
        float4v b2 = *reinterpret_cast<const float4v*>(qrB + 32);
        float4v b3 = *reinterpret_cast<const float4v*>(qrB + 36);
        #pragma unroll
        for (int j = 0; j < 4; ++j) {
            qa0[j]     = (short)f2bf(a0[j]);
            qa0[4 + j] = (short)f2bf(a1[j]);
            qa1[j]     = (short)f2bf(a2[j]);
            qa1[4 + j] = (short)f2bf(a3[j]);
            qb0[j]     = (short)f2bf(b0[j]);
            qb0[4 + j] = (short)f2bf(b1[j]);
            qb1[j]     = (short)f2bf(b2[j]);
            qb1[4 + j] = (short)f2bf(b3[j]);
        }
    }

    // K staging (sweep 2): 256 thr, 4 pieces (rows tid>>2 and +64, bytes (tid&3)*16, +64)
    const int krow  = tid >> 2;             // 0..63
    const int kby0  = (tid & 3) * 16;
    const int ksw   = (krow & 7) << 4;      // same for krow and krow+64
    const int kbiA0 = krow * 64 + (((kby0)      ^ ksw) >> 1);
    const int kbiA1 = krow * 64 + (((kby0 + 64) ^ ksw) >> 1);
    const int kbiB0 = (krow + 64) * 64 + (((kby0)      ^ ksw) >> 1);
    const int kbiB1 = (krow + 64) * 64 + (((kby0 + 64) ^ ksw) >> 1);
    const unsigned short* ksrcb = Kbf + base + (size_t)krow * D_K + (kby0 >> 1);

    // V staging: 4 pieces (row tid>>2, bytes (tid&3)*16 + j*64)
    const int vrow  = tid >> 2;             // 0..63
    const int vsw   = (vrow & 15) << 4;
    const int vby0  = (tid & 3) * 16;
    int vbi[4];
    #pragma unroll
    for (int j = 0; j < 4; ++j)
        vbi[j] = vrow * 128 + (((vby0 + j * 64) ^ vsw) >> 1);
    const unsigned short* vsrcb = VT + (size_t)bh * D_K * VT_STRIDE
                                     + (size_t)vrow * VT_STRIDE + (vby0 >> 1);

    // read-side swizzle constants
    const int kswz = (lq & 7) << 4;
    const int koff0 = ((lg * 16)      ^ kswz) >> 1;
    const int koff1 = ((64 + lg * 16) ^ kswz) >> 1;
    const int vswz = lq << 4;

    // ================= sweep 1: row sums (CH1=256, 8 chunks, both groups share K reads)
    float sA0 = 0.f, sA1 = 0.f, sB0 = 0.f, sB1 = 0.f;
    for (int c = 0; c < NCH1; ++c) {
        const unsigned short* kc = ksrcb + (size_t)c * CH1 * D_K;
        short8v r0 = *reinterpret_cast<const short8v*>(kc);
        short8v r1 = *reinterpret_cast<const short8v*>(kc + 32);
        short8v r2 = *reinterpret_cast<const short8v*>(kc + (size_t)64 * D_K);
        short8v r3 = *reinterpret_cast<const short8v*>(kc + (size_t)64 * D_K + 32);
        short8v r4 = *reinterpret_cast<const short8v*>(kc + (size_t)128 * D_K);
        short8v r5 = *reinterpret_cast<const short8v*>(kc + (size_t)128 * D_K + 32);
        short8v r6 = *reinterpret_cast<const short8v*>(kc + (size_t)192 * D_K);
        short8v r7 = *reinterpret_cast<const short8v*>(kc + (size_t)192 * D_K + 32);
        wg_sync_lds();
        *reinterpret_cast<short8v*>(&sbuf[kbiA0]) = r0;
        *reinterpret_cast<short8v*>(&sbuf[kbiA1]) = r1;
        *reinterpret_cast<short8v*>(&sbuf[kbiB0]) = r2;
        *reinterpret_cast<short8v*>(&sbuf[kbiB1]) = r3;
        *reinterpret_cast<short8v*>(&sbuf[8192 + kbiA0]) = r4;
        *reinterpret_cast<short8v*>(&sbuf[8192 + kbiA1]) = r5;
        *reinterpret_cast<short8v*>(&sbuf[8192 + kbiB0]) = r6;
        *reinterpret_cast<short8v*>(&sbuf[8192 + kbiB1]) = r7;
        wg_sync_lds();
        #pragma unroll
        for (int kt = 0; kt < 16; ++kt) {
            const int kl = kt * 16 + lq;
            short8v k0 = *reinterpret_cast<const short8v*>(&sbuf[kl * 64 + koff0]);
            short8v k1 = *reinterpret_cast<const short8v*>(&sbuf[kl * 64 + koff1]);
            float4v aA = (float4v)0.0f, aB = (float4v)0.0f;
            aA = __builtin_amdgcn_mfma_f32_16x16x32_bf16(k0, qa0, aA, 0, 0, 0);
            aA = __builtin_amdgcn_mfma_f32_16x16x32_bf16(k1, qa1, aA, 0, 0, 0);
            aB = __builtin_amdgcn_mfma_f32_16x16x32_bf16(k0, qb0, aB, 0, 0, 0);
            aB = __builtin_amdgcn_mfma_f32_16x16x32_bf16(k1, qb1, aB, 0, 0, 0);
            sA0 += exp2f(aA[0] * CEXP) + exp2f(aA[1] * CEXP);
            sA1 += exp2f(aA[2] * CEXP) + exp2f(aA[3] * CEXP);
            sB0 += exp2f(aB[0] * CEXP) + exp2f(aB[1] * CEXP);
            sB1 += exp2f(aB[2] * CEXP) + exp2f(aB[3] * CEXP);
        }
    }
    float sA = sA0 + sA1, sB = sB0 + sB1;
    sA += __shfl_xor(sA, 16, 64);
    sA += __shfl_xor(sA, 32, 64);
    sB += __shfl_xor(sB, 16, 64);
    sB += __shfl_xor(sB, 32, 64);
    const float rsA = 1.0f / sA;
    const float rsB = 1.0f / sB;

    // ================= sweep 2: attn + PV + ctx =================
    float4v caccA[4], caccB[4];
    #pragma unroll
    for (int dt = 0; dt < 4; ++dt) { caccA[dt] = (float4v)0.0f; caccB[dt] = (float4v)0.0f; }

    float* attnb = attn + (size_t)bh * S_LEN * S_LEN;

    for (int c = 0; c < NCHUNK; ++c) {
        const unsigned short* kc = ksrcb + (size_t)c * CH * D_K;
        short8v r0 = *reinterpret_cast<const short8v*>(kc);
        short8v r1 = *reinterpret_cast<const short8v*>(kc + 32);
        short8v r2 = *reinterpret_cast<const short8v*>(kc + (size_t)64 * D_K);
        short8v r3 = *reinterpret_cast<const short8v*>(kc + (size_t)64 * D_K + 32);
        short8v v0 = *reinterpret_cast<const short8v*>(vsrcb + c * CH);
        short8v v1 = *reinterpret_cast<const short8v*>(vsrcb + c * CH + 32);
        short8v v2 = *reinterpret_cast<const short8v*>(vsrcb + c * CH + 64);
        short8v v3 = *reinterpret_cast<const short8v*>(vsrcb + c * CH + 96);
        wg_sync_lds();
        *reinterpret_cast<short8v*>(&kbuf[kbiA0]) = r0;
        *reinterpret_cast<short8v*>(&kbuf[kbiA1]) = r1;
        *reinterpret_cast<short8v*>(&kbuf[kbiB0]) = r2;
        *reinterpret_cast<short8v*>(&kbuf[kbiB1]) = r3;
        *reinterpret_cast<short8v*>(&vbuf[vbi[0]]) = v0;
        *reinterpret_cast<short8v*>(&vbuf[vbi[1]]) = v1;
        *reinterpret_cast<short8v*>(&vbuf[vbi[2]]) = v2;
        *reinterpret_cast<short8v*>(&vbuf[vbi[3]]) = v3;
        wg_sync_lds();

        #pragma unroll
        for (int s2 = 0; s2 < 4; ++s2) {
            // 2 score tiles -> normalized bf16 P into pbw (both groups)
            #pragma unroll
            for (int t = 0; t < 2; ++t) {
                const int kt = s2 * 2 + t;
                const int kl = kt * 16 + lq;
                short8v k0 = *reinterpret_cast<const short8v*>(&kbuf[kl * 64 + koff0]);
                short8v k1 = *reinterpret_cast<const short8v*>(&kbuf[kl * 64 + koff1]);
                float4v aA = (float4v)0.0f, aB = (float4v)0.0f;
                aA = __builtin_amdgcn_mfma_f32_16x16x32_bf16(k0, qa0, aA, 0, 0, 0);
                aA = __builtin_amdgcn_mfma_f32_16x16x32_bf16(k1, qa1, aA, 0, 0, 0);
                aB = __builtin_amdgcn_mfma_f32_16x16x32_bf16(k0, qb0, aB, 0, 0, 0);
                aB = __builtin_amdgcn_mfma_f32_16x16x32_bf16(k1, qb1, aB, 0, 0, 0);
                uint2 pA, pB;
                pA.x = (unsigned)f2bf(exp2f(aA[0] * CEXP) * rsA)
                     | ((unsigned)f2bf(exp2f(aA[1] * CEXP) * rsA) << 16);
                pA.y = (unsigned)f2bf(exp2f(aA[2] * CEXP) * rsA)
                     | ((unsigned)f2bf(exp2f(aA[3] * CEXP) * rsA) << 16);
                pB.x = (unsigned)f2bf(exp2f(aB[0] * CEXP) * rsB)
                     | ((unsigned)f2bf(exp2f(aB[1] * CEXP) * rsB) << 16);
                pB.y = (unsigned)f2bf(exp2f(aB[2] * CEXP) * rsB)
                     | ((unsigned)f2bf(exp2f(aB[3] * CEXP) * rsB) << 16);
                *reinterpret_cast<uint2*>(&pbw[w][lq][t * 16 + lg * 4]) = pA;
                *reinterpret_cast<uint2*>(&pbw[w][16 + lq][t * 16 + lg * 4]) = pB;
            }
            // attn flush: 32 rows x 32 cols; 128B contiguous per row.
            #pragma unroll
            for (int r2 = 0; r2 < 4; ++r2) {
                const int row = r2 * 8 + (lane >> 3);
                short4v p4 = *reinterpret_cast<const short4v*>(&pbw[w][row][(lane & 7) * 4]);
                float4v o;
                o[0] = bf2f((unsigned short)p4[0]);
                o[1] = bf2f((unsigned short)p4[1]);
                o[2] = bf2f((unsigned short)p4[2]);
                o[3] = bf2f((unsigned short)p4[3]);
                *reinterpret_cast<float4v*>(
                    &attnb[(size_t)(qg0 + row) * S_LEN + c * CH + s2 * 32 + (lane & 7) * 4]) = o;
            }
            // PV: bv read ONCE, used by both groups
            short8v paA = *reinterpret_cast<const short8v*>(&pbw[w][lq][lg * 8]);
            short8v paB = *reinterpret_cast<const short8v*>(&pbw[w][16 + lq][lg * 8]);
            #pragma unroll
            for (int dt = 0; dt < 4; ++dt) {
                const int d = dt * 16 + lq;
                short8v bv = *reinterpret_cast<const short8v*>(
                    &vbuf[d * 128 + (((s2 * 64 + lg * 16) ^ vswz) >> 1)]);
                caccA[dt] = __builtin_amdgcn_mfma_f32_16x16x32_bf16(paA, bv, caccA[dt], 0, 0, 0);
                caccB[dt] = __builtin_amdgcn_mfma_f32_16x16x32_bf16(paB, bv, caccB[dt], 0, 0, 0);
            }
        }
    }

    // ---- ctx: wave-owned rows, direct stores
    float* ctxb = ctx + base;
    #pragma unroll
    for (int dt = 0; dt < 4; ++dt)
        #pragma unroll
        for (int r = 0; r < 4; ++r) {
            ctxb[(size_t)(qg0 + lg * 4 + r) * D_K + dt * 16 + lq] = caccA[dt][r];
            ctxb[(size_t)(qg0 + 16 + lg * 4 + r) * D_K + dt * 16 + lq] = caccB[dt][r];
        }
}

// ---------------- fallback (no workspace): self-contained ----------------
__global__ __launch_bounds__(512)
void sdpa_fallback_kernel(const float* __restrict__ Qp, const float* __restrict__ Kp,
                          const float* __restrict__ Vp,
                          float* __restrict__ ctx, float* __restrict__ attn) {
    const int qt = blockIdx.x, bh = blockIdx.y, tid = threadIdx.x;
    const int w = tid >> 6, lane = tid & 63, lq = lane & 15, lg = lane >> 4;
    const int qg = qt * 16, kw = w * 256;
    const size_t base = (size_t)bh * S_LEN * D_K;
    __shared__ __align__(16) char smem_raw[8 * 16 * 136 * 2];
    __shared__ float red_s[16][8];
    auto pbuf = reinterpret_cast<unsigned short(*)[16][136]>(smem_raw);
    auto ctxp = reinterpret_cast<float(*)[16][64]>(smem_raw);

    short8v q0, q1;
    {
        const float* qr = Qp + base + (size_t)(qg + lq) * D_K + lg * 8;
        #pragma unroll
        for (int j = 0; j < 8; ++j) { q0[j] = (short)f2bf(qr[j]); q1[j] = (short)f2bf(qr[32 + j]); }
    }
    float4v acc[16];
    #pragma unroll
    for (int kt = 0; kt < 16; ++kt) acc[kt] = (float4v)0.0f;
    #pragma unroll
    for (int kt = 0; kt < 16; ++kt) {
        const float* kr = Kp + base + (size_t)(kw + kt * 16 + lq) * D_K + lg * 8;
        short8v k0, k1;
        #pragma unroll
        for (int j = 0; j < 8; ++j) { k0[j] = (short)f2bf(kr[j]); k1[j] = (short)f2bf(kr[32 + j]); }
        acc[kt] = __builtin_amdgcn_mfma_f32_16x16x32_bf16(k0, q0, acc[kt], 0, 0, 0);
        acc[kt] = __builtin_amdgcn_mfma_f32_16x16x32_bf16(k1, q1, acc[kt], 0, 0, 0);
    }
    float s = 0.f;
    #pragma unroll
    for (int kt = 0; kt < 16; ++kt)
        #pragma unroll
        for (int r = 0; r < 4; ++r) {
            float p = exp2f(acc[kt][r] * CEXP);
            acc[kt][r] = p; s += p;
        }
    s += __shfl_xor(s, 16, 64);
    s += __shfl_xor(s, 32, 64);
    if (lane < 16) red_s[lane][w] = s;
    __syncthreads();
    float gs = red_s[lq][0];
    #pragma unroll
    for (int ww = 1; ww < 8; ++ww) gs += red_s[lq][ww];
    const float rsv = 1.0f / gs;
    #pragma unroll
    for (int kt = 0; kt < 16; ++kt) acc[kt] = acc[kt] * rsv;

    float4v cacc[4];
    #pragma unroll
    for (int dt = 0; dt < 4; ++dt) cacc[dt] = (float4v)0.0f;
    #pragma unroll
    for (int half = 0; half < 2; ++half) {
        #pragma unroll
        for (int kth = 0; kth < 8; ++kth) {
            const int kt = half * 8 + kth;
            unsigned p01 = (unsigned)f2bf(acc[kt][0]) | ((unsigned)f2bf(acc[kt][1]) << 16);
            unsigned p23 = (unsigned)f2bf(acc[kt][2]) | ((unsigned)f2bf(acc[kt][3]) << 16);
            unsigned* dst = reinterpret_cast<unsigned*>(&pbuf[w][lq][kth * 16 + lg * 4]);
            dst[0] = p01; dst[1] = p23;
        }
        #pragma unroll
        for (int s2 = 0; s2 < 4; ++s2) {
            short8v pa = *reinterpret_cast<const short8v*>(&pbuf[w][lq][s2 * 32 + lg * 8]);
            const int kk = kw + half * 128 + s2 * 32 + lg * 8;
            #pragma unroll
            for (int dt = 0; dt < 4; ++dt) {
                short8v bv;
                #pragma unroll
                for (int j = 0; j < 8; ++j)
                    bv[j] = (short)f2bf(Vp[base + (size_t)(kk + j) * D_K + dt * 16 + lq]);
                cacc[dt] = __builtin_amdgcn_mfma_f32_16x16x32_bf16(pa, bv, cacc[dt], 0, 0, 0);
            }
        }
    }
    __syncthreads();
    #pragma unroll
    for (int dt = 0; dt < 4; ++dt)
        #pragma unroll
        for (int r = 0; r < 4; ++r)
            ctxp[w][lg * 4 + r][dt * 16 + lq] = cacc[dt][r];
    __syncthreads();
    float* ctxb = ctx + base;
    for (int idx = tid; idx < 16 * 64; idx += 512) {
        const int q = idx >> 6, d = idx & 63;
        float sum = 0.f;
        #pragma unroll
        for (int ww = 0; ww < 8; ++ww) sum += ctxp[ww][q][d];
        ctxb[(size_t)(qg + q) * D_K + d] = sum;
    }
    float* attnb = attn + (size_t)bh * S_LEN * S_LEN + (size_t)(qg + lq) * S_LEN + kw + lg * 4;
    #pragma unroll
    for (int kt = 0; kt < 16; ++kt)
        *reinterpret_cast<float4v*>(attnb + kt * 16) = acc[kt];
}

extern "C" void kernel_launch(void* const* d_in, const int* in_sizes, int n_in,
                              void* d_out, int out_size, void* d_ws, size_t ws_size,
                              hipStream_t stream) {
    const float* Q = (const float*)d_in[0];
    const float* K = (const float*)d_in[1];
    const float* V = (const float*)d_in[2];
    float* ctx  = (float*)d_out;
    float* attn = ctx + (size_t)NBH * S_LEN * D_K;

    const size_t nel  = (size_t)NBH * S_LEN * D_K;       // 6,291,456
    const size_t nvt  = (size_t)NBH * D_K * VT_STRIDE;
    const size_t need = (nel + nvt) * 2;

    if (ws_size >= need) {
        unsigned short* Kbf = (unsigned short*)d_ws;
        unsigned short* VT  = Kbf + nel;
        conv_k_kernel<<<2048, 256, 0, stream>>>(K, Kbf);
        trans_v_kernel<<<dim3(32, 48), 256, 0, stream>>>(V, VT);
        sdpa_fused_kernel<<<dim3(16, 48), 256, 0, stream>>>(Q, Kbf, VT, ctx, attn);
    } else {
        sdpa_fallback_kernel<<<dim3(128, 48), 512, 0, stream>>>(Q, K, V, ctx, attn);
    }
}